// Round 5
// baseline (11.215 us; speedup 1.0000x reference)
//
#include <hip/hip_runtime.h>

// out = (1/N) * sum_i softplus(-input[i, label[i]])
// Two kernel nodes (proven fastest structure), micro-trimmed:
//   k1: 256 blocks x 256 threads; int2 label load, 2 independent gathers per
//       lane (ILP), pure wave-shuffle reduce -> partial[waveId] (1024 waves).
//       No LDS, no __syncthreads, 32-bit address arithmetic.
//   k2: ONE wave (64 threads): coalesced float4 reads of 1024 partials,
//       shuffle reduce only, write out. No LDS, no sync.

#define K1_BLOCKS 256
#define K1_THREADS 256
#define ROWS_PER_THREAD 2
#define NPARTIAL ((K1_BLOCKS * K1_THREADS) / 64)   // 1024 wave partials

__device__ __forceinline__ float wave_reduce(float v) {
    #pragma unroll
    for (int off = 32; off > 0; off >>= 1)
        v += __shfl_down(v, off, 64);
    return v;
}

__device__ __forceinline__ float softplus_neg(float x) {
    const float z = -x;
    return fmaxf(z, 0.f) + log1pf(expf(-fabsf(z)));
}

__global__ void __launch_bounds__(K1_THREADS)
softplus_gather_partial(const float* __restrict__ input,
                        const int* __restrict__ label,
                        float* __restrict__ partial,
                        int N, int C) {
    const int gid = blockIdx.x * K1_THREADS + threadIdx.x;
    const int r0 = gid * ROWS_PER_THREAD;
    float acc = 0.f;
    if (r0 + 1 < N) {
        // coalesced 8B label load, then two independent gathers (both in
        // flight under one vmcnt before either softplus).
        const int2 lab = ((const int2*)label)[gid];
        const unsigned o0 = (unsigned)(r0 * C) + (unsigned)lab.x;       // fits 32b
        const unsigned o1 = (unsigned)(r0 * C) + (unsigned)C + (unsigned)lab.y;
        const float x0 = input[o0];
        const float x1 = input[o1];
        acc = softplus_neg(x0) + softplus_neg(x1);
    } else {
        for (int i = r0; i < N; ++i)
            acc += softplus_neg(input[(long long)i * C + label[i]]);
    }
    acc = wave_reduce(acc);
    if ((threadIdx.x & 63) == 0)
        partial[gid >> 6] = acc;   // 1024 wave partials, no LDS / sync
}

__global__ void __launch_bounds__(64)
final_reduce(const float* __restrict__ partial, float* __restrict__ out,
             float invN) {
    // 1024 floats = 256 float4; 64 lanes x 4 coalesced float4 loads each.
    const float4* p4 = (const float4*)partial;
    float acc = 0.f;
    #pragma unroll
    for (int j = 0; j < 4; ++j) {
        const float4 v = p4[threadIdx.x + j * 64];
        acc += (v.x + v.y) + (v.z + v.w);
    }
    acc = wave_reduce(acc);
    if (threadIdx.x == 0) out[0] = acc * invN;
}

extern "C" void kernel_launch(void* const* d_in, const int* in_sizes, int n_in,
                              void* d_out, int out_size, void* d_ws, size_t ws_size,
                              hipStream_t stream) {
    const float* input = (const float*)d_in[0];
    const int*   label = (const int*)d_in[1];
    const int N = in_sizes[1];               // 131072 rows
    const int C = in_sizes[0] / in_sizes[1]; // 1000 classes
    float* partial = (float*)d_ws;           // NPARTIAL floats = 4 KB

    softplus_gather_partial<<<K1_BLOCKS, K1_THREADS, 0, stream>>>(
        input, label, partial, N, C);
    final_reduce<<<1, 64, 0, stream>>>(partial, (float*)d_out, 1.0f / (float)N);
}